// Round 1
// baseline (1672.000 us; speedup 1.0000x reference)
//
#include <hip/hip_runtime.h>

// ToyMoE: E=8 experts, T=1024 tok, H=2048 hidden, I=4096 intermediate.
// out = (silu(x@Wg + bg) * (x@Wu + bu)) @ Wd + bd, per expert.
// Strategy: bf16 MFMA (threshold 1.2e4 admits bf16 floor-eps), m97 GEMM
// structure (128x128x64 tile, global_load_lds width=16, 16x16x32 MFMA).
// Weights transposed once to [N][K] bf16 so both MFMA operands read
// 8 contiguous-K bf16 per lane from LDS (ds_read_b128).

#define E_ 8
#define T_ 1024
#define H_ 2048
#define I_ 4096

typedef unsigned short ushort_t;
typedef unsigned int uint_t;
typedef float f32x4 __attribute__((ext_vector_type(4)));
typedef __bf16 bf16x8 __attribute__((ext_vector_type(8)));
typedef unsigned short ushort8 __attribute__((ext_vector_type(8)));

__device__ inline ushort_t f2bf(float f) {
  uint_t u = __float_as_uint(f);
  u += 0x7fffu + ((u >> 16) & 1u);   // RTNE
  return (ushort_t)(u >> 16);
}
__device__ inline float bf2f(ushort_t h) {
  return __uint_as_float(((uint_t)h) << 16);
}

// async global->LDS, 16B per lane; LDS dest is wave-uniform base + lane*16
__device__ inline void async_copy16(void* lds, const void* gptr) {
  __builtin_amdgcn_global_load_lds(
      (__attribute__((address_space(1))) void*)(void*)gptr,
      (__attribute__((address_space(3))) void*)lds,
      16, 0, 0);
}

// ---------------- fp32 -> bf16 straight convert (x) ----------------
__global__ __launch_bounds__(256) void cvt_kernel(const float* __restrict__ in,
                                                  ushort_t* __restrict__ out) {
  size_t base = (size_t)(blockIdx.x * 256 + threadIdx.x) * 8;
  f32x4 a = *(const f32x4*)(in + base);
  f32x4 b = *(const f32x4*)(in + base + 4);
  ushort8 o;
  o[0] = f2bf(a[0]); o[1] = f2bf(a[1]); o[2] = f2bf(a[2]); o[3] = f2bf(a[3]);
  o[4] = f2bf(b[0]); o[5] = f2bf(b[1]); o[6] = f2bf(b[2]); o[7] = f2bf(b[3]);
  *(ushort8*)(out + base) = o;
}

// -------- fp32 [E][R][C] -> bf16 [E][C][R] transpose+convert --------
// grid (C/32, R/64, E), block (32,8). LDS 64x33 fp32 tile.
__global__ __launch_bounds__(256) void transpose_kernel(
    const float* __restrict__ in, ushort_t* __restrict__ out, int R, int C) {
  __shared__ float tile[64][33];
  const int e = blockIdx.z;
  const float* inb = in + (size_t)e * R * C;
  ushort_t* outb = out + (size_t)e * R * C;
  const int c0 = blockIdx.x * 32, r0 = blockIdx.y * 64;
  const int tx = threadIdx.x, ty = threadIdx.y;
#pragma unroll
  for (int jr = 0; jr < 8; ++jr) {
    int row = ty + 8 * jr;
    tile[row][tx] = inb[(size_t)(r0 + row) * C + c0 + tx];
  }
  __syncthreads();
#pragma unroll
  for (int jo = 0; jo < 4; ++jo) {
    int cc = ty + 8 * jo;
    int rr = 2 * tx;
    ushort2 v;
    v.x = f2bf(tile[rr][cc]);
    v.y = f2bf(tile[rr + 1][cc]);
    *(ushort2*)&outb[(size_t)(c0 + cc) * R + r0 + rr] = v;
  }
}

// ---------------- bf16 MFMA GEMM, m97 structure ----------------
// C[M,N] = A[M,K] * B^T (B stored [N][K]) + bias[N]
// 128x128 tile, BK=64, 256 thr = 4 waves, each wave 64x64 via 4x4 MFMAs.
#define BM 128
#define BN 128
#define BK 64

template <bool OUT_BF16>
__global__ __launch_bounds__(256) void gemm_kernel(
    const ushort_t* __restrict__ A, const ushort_t* __restrict__ B,
    const float* __restrict__ bias, void* __restrict__ Cout,
    int M, int N, int K, int lda) {
  __shared__ ushort_t As[BM * BK];
  __shared__ ushort_t Bs[BN * BK];
  const int e = blockIdx.z;
  const ushort_t* Ab = A + (size_t)e * M * lda;
  const ushort_t* Bb = B + (size_t)e * N * K;
  const float* biasb = bias + (size_t)e * N;
  const int m0 = blockIdx.y * BM;
  const int n0 = blockIdx.x * BN;
  const int tid = threadIdx.x;
  const int wv = tid >> 6, lane = tid & 63;
  const int wm = (wv >> 1) * 64, wn = (wv & 1) * 64;
  const int quad = lane >> 4, lr = lane & 15;

  f32x4 acc[4][4] = {};

  for (int k0 = 0; k0 < K; k0 += BK) {
#pragma unroll
    for (int r = 0; r < 4; ++r) {
      int chunk = r * 256 + tid;      // 0..1023, 16B each
      int row = chunk >> 3;           // 0..127
      int kc = (chunk & 7) * 8;       // element offset in tile K
      async_copy16(&As[chunk * 8], &Ab[(size_t)(m0 + row) * lda + k0 + kc]);
      async_copy16(&Bs[chunk * 8], &Bb[(size_t)(n0 + row) * K + k0 + kc]);
    }
    __syncthreads();   // drains vmcnt before barrier -> LDS valid
#pragma unroll
    for (int ks = 0; ks < 2; ++ks) {
      bf16x8 af[4], bfr[4];
#pragma unroll
      for (int i = 0; i < 4; ++i)
        af[i] = *(const bf16x8*)&As[(wm + 16 * i + lr) * BK + ks * 32 + quad * 8];
#pragma unroll
      for (int j = 0; j < 4; ++j)
        bfr[j] = *(const bf16x8*)&Bs[(wn + 16 * j + lr) * BK + ks * 32 + quad * 8];
#pragma unroll
      for (int i = 0; i < 4; ++i)
#pragma unroll
        for (int j = 0; j < 4; ++j)
          acc[i][j] = __builtin_amdgcn_mfma_f32_16x16x32_bf16(
              af[i], bfr[j], acc[i][j], 0, 0, 0);
    }
    __syncthreads();
  }

  // epilogue: C/D layout col=lane&15, row=quad*4+reg (m89/m91-verified)
  ushort_t* Cb16 = (ushort_t*)Cout + (size_t)e * M * N;
  float* Cb32 = (float*)Cout + (size_t)e * M * N;
#pragma unroll
  for (int j = 0; j < 4; ++j) {
    int col = n0 + wn + 16 * j + lr;
    float bv = biasb[col];
#pragma unroll
    for (int i = 0; i < 4; ++i) {
      int rowb = m0 + wm + 16 * i + quad * 4;
#pragma unroll
      for (int r = 0; r < 4; ++r) {
        float v = acc[i][j][r] + bv;
        if constexpr (OUT_BF16)
          Cb16[(size_t)(rowb + r) * N + col] = f2bf(v);
        else
          Cb32[(size_t)(rowb + r) * N + col] = v;
      }
    }
  }
}

// ---------------- SwiGLU elementwise, in-place into gate half ----------------
// gu: [E*T][2I] bf16; hidden[t][i] = silu(gu[t][i]) * gu[t][I+i] -> gu[t][i]
__global__ __launch_bounds__(256) void silu_kernel(ushort_t* __restrict__ gu) {
  size_t gid = (size_t)blockIdx.x * 256 + threadIdx.x;
  size_t base = gid * 8;               // index into [E*T][I] space
  size_t row = base >> 12;             // / I_
  int ic = (int)(base & (I_ - 1));
  ushort_t* p = gu + row * (2 * I_) + ic;
  ushort8 g8 = *(const ushort8*)p;
  ushort8 u8 = *(const ushort8*)(p + I_);
  ushort8 h;
#pragma unroll
  for (int r = 0; r < 8; ++r) {
    float g = bf2f(g8[r]);
    float u = bf2f(u8[r]);
    float s = g / (1.0f + __expf(-g));
    h[r] = f2bf(s * u);
  }
  *(ushort8*)p = h;
}

extern "C" void kernel_launch(void* const* d_in, const int* in_sizes, int n_in,
                              void* d_out, int out_size, void* d_ws, size_t ws_size,
                              hipStream_t stream) {
  const float* x   = (const float*)d_in[0];  // [E][T][H]
  const float* wgu = (const float*)d_in[1];  // [E][H][2I]
  const float* bgu = (const float*)d_in[2];  // [E][2I]
  const float* wd  = (const float*)d_in[3];  // [E][I][H]
  const float* bd  = (const float*)d_in[4];  // [E][H]
  float* out = (float*)d_out;                // [E][T][H]

  char* ws = (char*)d_ws;
  // workspace layout (bytes):
  //   xb    :  33,554,432  (E*T*H bf16)
  //   wgu_t : 268,435,456  (E*2I*H bf16)
  //   wd_t  : 134,217,728  (E*H*I bf16)
  //   gu    : 134,217,728  (E*T*2I bf16; silu writes hidden in-place, lda=2I)
  // total 570,425,344
  ushort_t* xb    = (ushort_t*)(ws);
  ushort_t* wgu_t = (ushort_t*)(ws + 33554432);
  ushort_t* wd_t  = (ushort_t*)(ws + 33554432 + 268435456);
  ushort_t* gu    = (ushort_t*)(ws + 33554432 + 268435456 + 134217728);

  // 1) x -> bf16 (E*T*H = 16,777,216 elems / 8 per thread / 256)
  cvt_kernel<<<8192, 256, 0, stream>>>(x, xb);
  // 2) weights -> transposed bf16 [N][K]
  transpose_kernel<<<dim3(2 * I_ / 32, H_ / 64, E_), dim3(32, 8), 0, stream>>>(
      wgu, wgu_t, H_, 2 * I_);
  transpose_kernel<<<dim3(H_ / 32, I_ / 64, E_), dim3(32, 8), 0, stream>>>(
      wd, wd_t, I_, H_);
  // 3) gu = x @ Wgu + bgu   (M=1024, N=8192, K=2048) -> bf16
  gemm_kernel<true><<<dim3(2 * I_ / BN, T_ / BM, E_), 256, 0, stream>>>(
      xb, wgu_t, bgu, gu, T_, 2 * I_, H_, H_);
  // 4) SwiGLU in place (E*T*I = 33,554,432 elems / 8 / 256)
  silu_kernel<<<16384, 256, 0, stream>>>(gu);
  // 5) out = hidden @ Wd + bd (M=1024, N=2048, K=4096, lda=2I) -> fp32
  gemm_kernel<false><<<dim3(H_ / BN, T_ / BM, E_), 256, 0, stream>>>(
      gu, wd_t, bd, out, T_, H_, I_, 2 * I_);
}

// Round 2
// 1510.912 us; speedup vs baseline: 1.1066x; 1.1066x over previous
//
#include <hip/hip_runtime.h>

// ToyMoE: E=8, T=1024, H=2048, I=4096.
// R2: (1) XOR-swizzled LDS (16B-chunk granularity, global_load_lds-compatible)
//     to kill the 1.0e8 SQ_LDS_BANK_CONFLICT (row stride 128B = 32 banks);
// (2) SwiGLU fused into GEMM1 epilogue (gate+up tiles in one block);
// (3) transpose v2 with float4/ushort8 accesses + LDS swizzle.

#define E_ 8
#define T_ 1024
#define H_ 2048
#define I_ 4096

typedef unsigned short ushort_t;
typedef unsigned int uint_t;
typedef float f32x4 __attribute__((ext_vector_type(4)));
typedef __bf16 bf16x8 __attribute__((ext_vector_type(8)));
typedef unsigned short ushort8 __attribute__((ext_vector_type(8)));

__device__ inline ushort_t f2bf(float f) {
  uint_t u = __float_as_uint(f);
  u += 0x7fffu + ((u >> 16) & 1u);   // RTNE
  return (ushort_t)(u >> 16);
}

// async global->LDS, 16B per lane; LDS dest is wave-uniform base + lane*16
__device__ inline void async_copy16(void* lds, const void* gptr) {
  __builtin_amdgcn_global_load_lds(
      (__attribute__((address_space(1))) void*)(void*)gptr,
      (__attribute__((address_space(3))) void*)lds,
      16, 0, 0);
}

// LDS slot s (16B units) holds global k-chunk (s&7) ^ ((s>>3)&7) of row s>>3.
// Fragment reads then hit 2 lanes/bank (free, m136) instead of 16-way.
__device__ inline int swz_kc(int chunk) {
  return ((chunk & 7) ^ ((chunk >> 3) & 7)) * 8;   // element offset in row
}

// ---------------- fp32 -> bf16 straight convert (x) ----------------
__global__ __launch_bounds__(256) void cvt_kernel(const float* __restrict__ in,
                                                  ushort_t* __restrict__ out) {
  size_t base = (size_t)(blockIdx.x * 256 + threadIdx.x) * 8;
  f32x4 a = *(const f32x4*)(in + base);
  f32x4 b = *(const f32x4*)(in + base + 4);
  ushort8 o;
  o[0] = f2bf(a[0]); o[1] = f2bf(a[1]); o[2] = f2bf(a[2]); o[3] = f2bf(a[3]);
  o[4] = f2bf(b[0]); o[5] = f2bf(b[1]); o[6] = f2bf(b[2]); o[7] = f2bf(b[3]);
  *(ushort8*)(out + base) = o;
}

// -------- fp32 [E][R][C] -> bf16 [E][C][R] transpose+convert, 64x64 tile ----
// float4 reads, ushort8 writes; LDS float4-granular XOR swizzle:
// element (r,c) at word r*64 + 4*((c>>2)^(r>>3)) + (c&3) -> both phases 2-way.
__global__ __launch_bounds__(256) void transpose_kernel(
    const float* __restrict__ in, ushort_t* __restrict__ out, int R, int C) {
  __shared__ float tile[64 * 64];
  const int e = blockIdx.z;
  const float* inb = in + (size_t)e * R * C;
  ushort_t* outb = out + (size_t)e * R * C;
  const int c0 = blockIdx.x * 64, r0 = blockIdx.y * 64;
  const int t = threadIdx.x;
  const int lrow = t >> 4, lc4 = t & 15;  // load: 16 rows x 16 float4 cols
#pragma unroll
  for (int rr = 0; rr < 64; rr += 16) {
    int r = lrow + rr;
    f32x4 v = *(const f32x4*)&inb[(size_t)(r0 + r) * C + c0 + lc4 * 4];
    *(f32x4*)&tile[r * 64 + 4 * (lc4 ^ (r >> 3))] = v;
  }
  __syncthreads();
  const int oc = t >> 3, orr = (t & 7) * 8;  // store: col oc, 8 rows
#pragma unroll
  for (int cc = 0; cc < 64; cc += 32) {
    int c = oc + cc;
    ushort8 o;
#pragma unroll
    for (int k = 0; k < 8; ++k) {
      int r = orr + k;
      o[k] = f2bf(tile[r * 64 + 4 * ((c >> 2) ^ (r >> 3)) + (c & 3)]);
    }
    *(ushort8*)&outb[(size_t)(c0 + c) * R + r0 + orr] = o;
  }
}

#define G_BK 64

// ---------------- GEMM1 + bias + SwiGLU fused ----------------
// A=[E][T][H] bf16, B=wgu_t [E][2I][H] bf16 (N-major), out hidden [E][T][I] bf16.
// Block: 128(M) x 64(N, gate AND up). 4 waves, wave tile 64x32 per matrix.
__global__ __launch_bounds__(256) void gemm1_swiglu_kernel(
    const ushort_t* __restrict__ A, const ushort_t* __restrict__ B,
    const float* __restrict__ bias, ushort_t* __restrict__ Hd) {
  __shared__ ushort_t As[128 * G_BK];
  __shared__ ushort_t Bg[64 * G_BK];
  __shared__ ushort_t Bu[64 * G_BK];
  const int e = blockIdx.z;
  const ushort_t* Ab = A + (size_t)e * T_ * H_;
  const ushort_t* Bb = B + (size_t)e * (2 * I_) * H_;
  const float* biasb = bias + (size_t)e * 2 * I_;
  const int m0 = blockIdx.y * 128;
  const int n0 = blockIdx.x * 64;
  const int tid = threadIdx.x;
  const int wv = tid >> 6, lane = tid & 63;
  const int wm = (wv >> 1) * 64, wn = (wv & 1) * 32;
  const int quad = lane >> 4, lr = lane & 15;

  f32x4 accg[4][2] = {};
  f32x4 accu[4][2] = {};

  for (int k0 = 0; k0 < H_; k0 += G_BK) {
#pragma unroll
    for (int r = 0; r < 4; ++r) {
      int chunk = r * 256 + tid;            // 1024 chunks of A
      int row = chunk >> 3;
      async_copy16(&As[chunk * 8],
                   &Ab[(size_t)(m0 + row) * H_ + k0 + swz_kc(chunk)]);
    }
#pragma unroll
    for (int r = 0; r < 2; ++r) {
      int chunk = r * 256 + tid;            // 512 chunks each of Bg/Bu
      int row = chunk >> 3;
      int kc = k0 + swz_kc(chunk);
      async_copy16(&Bg[chunk * 8], &Bb[(size_t)(n0 + row) * H_ + kc]);
      async_copy16(&Bu[chunk * 8], &Bb[(size_t)(I_ + n0 + row) * H_ + kc]);
    }
    __syncthreads();
#pragma unroll
    for (int ks = 0; ks < 2; ++ks) {
      const int sw = ((ks * 4 + quad) ^ (lr & 7)) * 8;  // row&7 == lr&7
      bf16x8 af[4], bg[2], bu[2];
#pragma unroll
      for (int i = 0; i < 4; ++i)
        af[i] = *(const bf16x8*)&As[(wm + 16 * i + lr) * G_BK + sw];
#pragma unroll
      for (int j = 0; j < 2; ++j) {
        bg[j] = *(const bf16x8*)&Bg[(wn + 16 * j + lr) * G_BK + sw];
        bu[j] = *(const bf16x8*)&Bu[(wn + 16 * j + lr) * G_BK + sw];
      }
#pragma unroll
      for (int i = 0; i < 4; ++i)
#pragma unroll
        for (int j = 0; j < 2; ++j) {
          accg[i][j] = __builtin_amdgcn_mfma_f32_16x16x32_bf16(
              af[i], bg[j], accg[i][j], 0, 0, 0);
          accu[i][j] = __builtin_amdgcn_mfma_f32_16x16x32_bf16(
              af[i], bu[j], accu[i][j], 0, 0, 0);
        }
    }
    __syncthreads();
  }

  // epilogue: C/D layout col=lane&15, row=quad*4+reg (verified R1)
  ushort_t* Hb = Hd + (size_t)e * T_ * I_;
#pragma unroll
  for (int j = 0; j < 2; ++j) {
    int col = n0 + wn + 16 * j + lr;
    float bgv = biasb[col];
    float buv = biasb[I_ + col];
#pragma unroll
    for (int i = 0; i < 4; ++i) {
      int rowb = m0 + wm + 16 * i + quad * 4;
#pragma unroll
      for (int r = 0; r < 4; ++r) {
        float g = accg[i][j][r] + bgv;
        float u = accu[i][j][r] + buv;
        float s = g / (1.0f + __expf(-g));
        Hb[(size_t)(rowb + r) * I_ + col] = f2bf(s * u);
      }
    }
  }
}

// ---------------- GEMM2: out = hidden @ Wd^T + bd, fp32 out ----------------
// A=hidden [E][T][I] bf16, B=wd_t [E][H][I] bf16, out [E][T][H] fp32.
__global__ __launch_bounds__(256) void gemm2_kernel(
    const ushort_t* __restrict__ A, const ushort_t* __restrict__ B,
    const float* __restrict__ bias, float* __restrict__ C) {
  __shared__ ushort_t As[128 * G_BK];
  __shared__ ushort_t Bs[128 * G_BK];
  const int e = blockIdx.z;
  const ushort_t* Ab = A + (size_t)e * T_ * I_;
  const ushort_t* Bb = B + (size_t)e * H_ * I_;
  const float* biasb = bias + (size_t)e * H_;
  const int m0 = blockIdx.y * 128;
  const int n0 = blockIdx.x * 128;
  const int tid = threadIdx.x;
  const int wv = tid >> 6, lane = tid & 63;
  const int wm = (wv >> 1) * 64, wn = (wv & 1) * 64;
  const int quad = lane >> 4, lr = lane & 15;

  f32x4 acc[4][4] = {};

  for (int k0 = 0; k0 < I_; k0 += G_BK) {
#pragma unroll
    for (int r = 0; r < 4; ++r) {
      int chunk = r * 256 + tid;
      int row = chunk >> 3;
      int kc = k0 + swz_kc(chunk);
      async_copy16(&As[chunk * 8], &Ab[(size_t)(m0 + row) * I_ + kc]);
      async_copy16(&Bs[chunk * 8], &Bb[(size_t)(n0 + row) * I_ + kc]);
    }
    __syncthreads();
#pragma unroll
    for (int ks = 0; ks < 2; ++ks) {
      const int sw = ((ks * 4 + quad) ^ (lr & 7)) * 8;
      bf16x8 af[4], bfr[4];
#pragma unroll
      for (int i = 0; i < 4; ++i)
        af[i] = *(const bf16x8*)&As[(wm + 16 * i + lr) * G_BK + sw];
#pragma unroll
      for (int j = 0; j < 4; ++j)
        bfr[j] = *(const bf16x8*)&Bs[(wn + 16 * j + lr) * G_BK + sw];
#pragma unroll
      for (int i = 0; i < 4; ++i)
#pragma unroll
        for (int j = 0; j < 4; ++j)
          acc[i][j] = __builtin_amdgcn_mfma_f32_16x16x32_bf16(
              af[i], bfr[j], acc[i][j], 0, 0, 0);
    }
    __syncthreads();
  }

  float* Cb = C + (size_t)e * T_ * H_;
#pragma unroll
  for (int j = 0; j < 4; ++j) {
    int col = n0 + wn + 16 * j + lr;
    float bv = biasb[col];
#pragma unroll
    for (int i = 0; i < 4; ++i) {
      int rowb = m0 + wm + 16 * i + quad * 4;
#pragma unroll
      for (int r = 0; r < 4; ++r)
        Cb[(size_t)(rowb + r) * H_ + col] = acc[i][j][r] + bv;
    }
  }
}

extern "C" void kernel_launch(void* const* d_in, const int* in_sizes, int n_in,
                              void* d_out, int out_size, void* d_ws, size_t ws_size,
                              hipStream_t stream) {
  const float* x   = (const float*)d_in[0];  // [E][T][H]
  const float* wgu = (const float*)d_in[1];  // [E][H][2I]
  const float* bgu = (const float*)d_in[2];  // [E][2I]
  const float* wd  = (const float*)d_in[3];  // [E][I][H]
  const float* bd  = (const float*)d_in[4];  // [E][H]
  float* out = (float*)d_out;                // [E][T][H]

  char* ws = (char*)d_ws;
  // workspace: xb 32MB | wgu_t 256MB | wd_t 128MB | hidden 64MB = 480MB
  ushort_t* xb     = (ushort_t*)(ws);
  ushort_t* wgu_t  = (ushort_t*)(ws + 33554432);
  ushort_t* wd_t   = (ushort_t*)(ws + 33554432 + 268435456);
  ushort_t* hidden = (ushort_t*)(ws + 33554432 + 268435456 + 134217728);

  cvt_kernel<<<8192, 256, 0, stream>>>(x, xb);
  transpose_kernel<<<dim3(2 * I_ / 64, H_ / 64, E_), 256, 0, stream>>>(
      wgu, wgu_t, H_, 2 * I_);
  transpose_kernel<<<dim3(H_ / 64, I_ / 64, E_), 256, 0, stream>>>(
      wd, wd_t, I_, H_);
  gemm1_swiglu_kernel<<<dim3(I_ / 64, T_ / 128, E_), 256, 0, stream>>>(
      xb, wgu_t, bgu, hidden);
  gemm2_kernel<<<dim3(H_ / 128, T_ / 128, E_), 256, 0, stream>>>(
      hidden, wd_t, bd, out);
}